// Round 5
// baseline (8177.366 us; speedup 1.0000x reference)
//
#include <hip/hip_runtime.h>
#include <stdint.h>

#define T_STEPS 2048
#define BATCH   16
#define DIM     1024
#define BD      (BATCH * DIM)
#define SENTN   4096   // 16 batches * 256 sentinels, per parity

typedef float    f32x4 __attribute__((ext_vector_type(4)));
typedef unsigned u32x4 __attribute__((ext_vector_type(4)));
typedef __bf16   bf16x8 __attribute__((ext_vector_type(8)));

// ---------------------------------------------------------------------------
// ws: [0,256KB) hX = u64[2][B][D] tagged h values; [256KB,+32KB) sent u32[2][B][256]
// ---------------------------------------------------------------------------
__global__ void prep_kernel(const float* __restrict__ h0,
                            float* __restrict__ hout,
                            unsigned long long* __restrict__ hX,
                            unsigned* __restrict__ sent) {
  int i = blockIdx.x * blockDim.x + threadIdx.x;
  if (i < BD) {
    float v = h0[i];
    hout[i] = v;
    hX[i] = (unsigned long long)__float_as_uint(v);   // tag 0 | h0
    hX[BD + i] = 0xFFFFFFFF00000000ull;               // sentinel tag
  }
  if (i < SENTN) {
    sent[i] = 0u;                                     // parity 0: epoch 0 ready
    sent[SENTN + i] = 0xFFFFFFFFu;                    // parity 1: invalid
  }
}

// ---------------------------------------------------------------------------
// xp = x @ W_x^T + b  (R1-proven)
// ---------------------------------------------------------------------------
__global__ __launch_bounds__(256)
void xp_gemm(const float* __restrict__ X, const float* __restrict__ W,
             const float* __restrict__ Bv, float* __restrict__ XP) {
  __shared__ __bf16 As[128 * 64];
  __shared__ __bf16 Bs[128 * 64];
  const int tid = threadIdx.x;
  const int bm = blockIdx.x & 255;
  const int bn = blockIdx.x >> 8;
  const int w = tid >> 6, l = tid & 63;
  const int wr = w >> 1, wc = w & 1;
  const int sr = tid >> 1, sh = tid & 1;

  const float* xrow = X + (size_t)(bm * 128 + sr) * DIM + sh * 32;
  const float* wrow = W + (size_t)(bn * 128 + sr) * DIM + sh * 32;
  char* AsB = (char*)As;
  char* BsB = (char*)Bs;
  const int swr  = sr * 128;
  const int swzs = (sr & 7) << 4;

  f32x4 acc[4][4];
  const f32x4 z4 = {0.f, 0.f, 0.f, 0.f};
#pragma unroll
  for (int i = 0; i < 4; ++i)
#pragma unroll
    for (int j = 0; j < 4; ++j) acc[i][j] = z4;

  for (int kt = 0; kt < 16; ++kt) {
#pragma unroll
    for (int j = 0; j < 8; ++j) {
      f32x4 a  = *(const f32x4*)(xrow + kt * 64 + 4 * j);
      f32x4 bv = *(const f32x4*)(wrow + kt * 64 + 4 * j);
      union { __bf16 h[4]; unsigned long long u; } pa, pb;
#pragma unroll
      for (int qq = 0; qq < 4; ++qq) { pa.h[qq] = (__bf16)a[qq]; pb.h[qq] = (__bf16)bv[qq]; }
      int c2  = (sh * 32 + 4 * j) * 2;
      int off = swr + (c2 ^ swzs);
      *(unsigned long long*)(AsB + off) = pa.u;
      *(unsigned long long*)(BsB + off) = pb.u;
    }
    __syncthreads();
#pragma unroll
    for (int ks = 0; ks < 2; ++ks) {
      bf16x8 afr[4], bfr[4];
#pragma unroll
      for (int mi = 0; mi < 4; ++mi) {
        int row = wr * 64 + mi * 16 + (l & 15);
        int c2  = ks * 64 + (l >> 4) * 16;
        afr[mi] = *(const bf16x8*)(AsB + row * 128 + (c2 ^ ((row & 7) << 4)));
      }
#pragma unroll
      for (int ni = 0; ni < 4; ++ni) {
        int row = wc * 64 + ni * 16 + (l & 15);
        int c2  = ks * 64 + (l >> 4) * 16;
        bfr[ni] = *(const bf16x8*)(BsB + row * 128 + (c2 ^ ((row & 7) << 4)));
      }
#pragma unroll
      for (int mi = 0; mi < 4; ++mi)
#pragma unroll
        for (int ni = 0; ni < 4; ++ni)
          acc[mi][ni] = __builtin_amdgcn_mfma_f32_16x16x32_bf16(
              afr[mi], bfr[ni], acc[mi][ni], 0, 0, 0);
    }
    __syncthreads();
  }
  const int colb = bn * 128 + wc * 64 + (l & 15);
#pragma unroll
  for (int ni = 0; ni < 4; ++ni) {
    int col = colb + ni * 16;
    float bb = Bv[col];
#pragma unroll
    for (int mi = 0; mi < 4; ++mi) {
      int row = bm * 128 + wr * 64 + mi * 16 + ((l >> 4) << 2);
#pragma unroll
      for (int r = 0; r < 4; ++r)
        XP[(size_t)(row + r) * DIM + col] = acc[mi][ni][r] + bb;
    }
  }
}

// bijective LDS word swizzle: 8 consecutive lanes -> 8 distinct bank quads
__device__ __forceinline__ int swz_word(int c) {
  int q = c >> 2;
  return (c & 3) | (((q ^ (q >> 3)) & 255) << 2);
}

// ---------------------------------------------------------------------------
// recurrence, Path C: per-wave sentinel polls (64B) + validated 512B slice load.
// Producer side is fire-and-forget (no fences); consumer validates data tags.
// t=0 own-slice comes from an h0 preload (the R4 bug: it was never loaded).
// ---------------------------------------------------------------------------
__global__ __launch_bounds__(1024, 4)
void rnn_kernel(const float* __restrict__ Wh, const float* __restrict__ Z,
                const float* __restrict__ gz, const float* __restrict__ gh,
                const float* __restrict__ bg, const float* __restrict__ h0,
                float* __restrict__ out,    // holds xp, overwritten with out
                float* __restrict__ hout,   // [T+1][B][D]
                unsigned long long* __restrict__ hX,
                unsigned* __restrict__ sent) {
  __shared__ float hb[2][1024];
  const int tid = threadIdx.x;
  const int w   = tid >> 6;
  const int l   = tid & 63;
  const int b   = blockIdx.x >> 4;
  const int s   = blockIdx.x & 15;
  const int r0  = s * 64;
  const int q   = (s + w) & 15;          // slice this wave fetches (w=0: own)
  const int myrow  = r0 + w * 4 + (l & 3);
  const bool writer = (l < 4);

  // W_h slice -> registers: wave w rows r0+4w..+3, lane l K-range [16l,16l+16)
  f32x4 W4[4][4];
  {
    const f32x4* WhV = (const f32x4*)Wh;
#pragma unroll
    for (int r4 = 0; r4 < 4; ++r4) {
      size_t base = (size_t)(r0 + w * 4 + r4) * (DIM / 4) + l * 4;
#pragma unroll
      for (int jj = 0; jj < 4; ++jj) W4[r4][jj] = WhV[base + jj];
    }
  }

  // t=0 preload: own slice s of hb[0] from h0 (stream-ordered after prep).
  if (w == 0) hb[0][swz_word(r0 + l)] = h0[(size_t)b * DIM + r0 + l];

  float cgz = 0.f, cgh = 0.f, cbg = 0.f, xp_n = 0.f, z_n = 0.f;
  if (writer) {
    cgz = gz[myrow]; cgh = gh[myrow]; cbg = bg[myrow];
    xp_n = out[(size_t)b * DIM + myrow];   // xp[0,b,myrow]
    z_n  = Z[(size_t)b * DIM + myrow];
  }

  for (int t = 0; t < T_STEPS; ++t) {
    const int p  = t & 1;
    const int p1 = p ^ 1;
    const unsigned tt = (unsigned)t;
    const unsigned long long* src = hX + (size_t)p * BD + (size_t)b * DIM;
    unsigned long long*       dst = hX + (size_t)p1 * BD + (size_t)b * DIM;

    if (w != 0) {
      // 1) detect slice q ready: 16 per-producer-wave sentinels (64B round)
      const unsigned* sp = sent + p * SENTN + b * 256 + q * 16 + (l & 15);
      unsigned sv;
      for (;;) {
        asm volatile("global_load_dword %0, %1, off sc1\n\ts_waitcnt vmcnt(0)"
                     : "=v"(sv) : "v"(sp) : "memory");
        if (__all(sv == tt)) break;
        __builtin_amdgcn_s_sleep(1);
      }
      // 2) validated slice load (data carries tags; retry absorbs reorder)
      const unsigned long long* ap = src + q * 64 + l;
      unsigned long long v;
      for (;;) {
        asm volatile("global_load_dwordx2 %0, %1, off sc1\n\ts_waitcnt vmcnt(0)"
                     : "=v"(v) : "v"(ap) : "memory");
        if (__all((unsigned)(v >> 32) == tt)) break;
        __builtin_amdgcn_s_sleep(1);
      }
      hb[p][swz_word(q * 64 + l)] = __uint_as_float((unsigned)v);
    }
    __syncthreads();

    // matvec: 64 FMA/thread from swizzled LDS
    float acc0 = 0.f, acc1 = 0.f, acc2 = 0.f, acc3 = 0.f;
#pragma unroll
    for (int jj = 0; jj < 4; ++jj) {
      int qr = 4 * l + jj;
      int wb = ((qr ^ (qr >> 3)) & 255) << 2;
      f32x4 h4 = *(const f32x4*)&hb[p][wb];
#pragma unroll
      for (int i = 0; i < 4; ++i) {
        acc0 = fmaf(W4[0][jj][i], h4[i], acc0);
        acc1 = fmaf(W4[1][jj][i], h4[i], acc1);
        acc2 = fmaf(W4[2][jj][i], h4[i], acc2);
        acc3 = fmaf(W4[3][jj][i], h4[i], acc3);
      }
    }
    // 7-shuffle multi-reduce: lane l ends with full 64-lane sum of acc_{l&3}
    float w01 = (l & 1) ? acc0 : acc1;
    float v01 = ((l & 1) ? acc1 : acc0) + __shfl_xor(w01, 1);
    float w23 = (l & 1) ? acc2 : acc3;
    float v23 = ((l & 1) ? acc3 : acc2) + __shfl_xor(w23, 1);
    float wv  = (l & 2) ? v01 : v23;
    float vv  = ((l & 2) ? v23 : v01) + __shfl_xor(wv, 2);
    vv += __shfl_xor(vv, 4);
    vv += __shfl_xor(vv, 8);
    vv += __shfl_xor(vv, 16);
    vv += __shfl_xor(vv, 32);

    if (writer) {
      float pre = vv + xp_n;
      float e2 = __expf(2.0f * pre);
      float hn = 1.0f - 2.0f / (e2 + 1.0f);          // tanh, overflow-safe
      unsigned long long pk = ((unsigned long long)(unsigned)(t + 1) << 32)
                            | (unsigned long long)__float_as_uint(hn);
      __hip_atomic_store(&dst[myrow], pk, __ATOMIC_RELAXED, __HIP_MEMORY_SCOPE_AGENT);
      hb[p1][swz_word(myrow)] = hn;                  // own slice -> LDS directly
      hout[((size_t)(t + 1) * BATCH + b) * DIM + myrow] = hn;
      float y   = z_n * cgz + hn * cgh + cbg;
      float sig = 1.0f / (1.0f + __expf(-y));
      out[((size_t)t * BATCH + b) * DIM + myrow] = hn * (y * sig);
      if (t + 1 < T_STEPS) {   // prefetch next step's xp, z off the hot path
        xp_n = out[((size_t)(t + 1) * BATCH + b) * DIM + myrow];
        z_n  = Z[((size_t)(t + 1) * BATCH + b) * DIM + myrow];
      }
    }
    // per-wave sentinel (fire-and-forget; consumers validate data tags anyway)
    if (l == 0) {
      __hip_atomic_store(&sent[p1 * SENTN + b * 256 + s * 16 + w],
                         (unsigned)(t + 1), __ATOMIC_RELAXED, __HIP_MEMORY_SCOPE_AGENT);
    }
  }
}

extern "C" void kernel_launch(void* const* d_in, const int* in_sizes, int n_in,
                              void* d_out, int out_size, void* d_ws, size_t ws_size,
                              hipStream_t stream) {
  const float* x    = (const float*)d_in[0];
  const float* z    = (const float*)d_in[1];
  const float* h0   = (const float*)d_in[2];
  const float* Wx   = (const float*)d_in[3];
  const float* Wh   = (const float*)d_in[4];
  const float* bias = (const float*)d_in[5];
  const float* gz   = (const float*)d_in[6];
  const float* gh   = (const float*)d_in[7];
  const float* bg   = (const float*)d_in[8];

  float* out  = (float*)d_out;
  float* hout = out + (size_t)T_STEPS * BATCH * DIM;
  unsigned long long* hX = (unsigned long long*)d_ws;           // 256 KB
  unsigned* sent = (unsigned*)((char*)d_ws + 2ull * BD * 8ull); // 32 KB

  prep_kernel<<<dim3(64), dim3(256), 0, stream>>>(h0, hout, hX, sent);
  xp_gemm<<<dim3(2048), dim3(256), 0, stream>>>(x, Wx, bias, out);
  rnn_kernel<<<dim3(256), dim3(1024), 0, stream>>>(Wh, z, gz, gh, bg, h0, out, hout, hX, sent);
}